// Round 6
// baseline (444.421 us; speedup 1.0000x reference)
//
#include <hip/hip_runtime.h>
#include <stdint.h>

#define VOCAB 16384
#define NB 32
#define NTOK 8224      // 32*257
#define MTILES 65      // M tiles of 128 rows
#define MP 8320        // MTILES*128
#define NBY 128        // N tiles of 128 cols
#define TILE_BYTES 65536    // 128 rows x 256 K x 2B f16 (hi plane)
#define PHASE_BYTES 16384   // K64 phase
#define MWIN 2.2e-3f        // rigorous |sim_f16 - sim_fp32| window (2*margin)

typedef _Float16 half8 __attribute__((ext_vector_type(8)));
typedef float f4 __attribute__((ext_vector_type(4)));
typedef __attribute__((address_space(1))) const uint32_t* gas_t;
typedef __attribute__((address_space(3))) uint32_t* las_t;

__device__ __forceinline__ void async16(const void* g, void* l) {
    __builtin_amdgcn_global_load_lds((gas_t)g, (las_t)l, 16, 0, 0);
}

__device__ __forceinline__ unsigned long long key64(float v, int idx) {
    unsigned u = __float_as_uint(v);
    u = (u & 0x80000000u) ? ~u : (u | 0x80000000u);
    return ((unsigned long long)u << 32) | (unsigned)(~idx);   // order: val desc, idx asc
}

// ---------- tok build: patch transpose + class rows fused ----------
__global__ __launch_bounds__(256) void k_patch(const float* __restrict__ cls, const float* __restrict__ patch,
                                               float* __restrict__ tok) {
    __shared__ float t[64][65];
    int c0 = blockIdx.x * 64, p0 = blockIdx.y * 64, b = blockIdx.z;
    int tid = threadIdx.x;
    int l = tid & 63, w = tid >> 6;
    const float* src = patch + b * 65536;
#pragma unroll
    for (int i = 0; i < 16; ++i) {
        int row = i * 4 + w;
        t[row][l] = src[(c0 + row) * 256 + p0 + l];
    }
    if (blockIdx.y == 0 && tid < 64)
        tok[(b * 257) * 256 + c0 + tid] = cls[b * 256 + c0 + tid];   // class token row
    __syncthreads();
#pragma unroll
    for (int i = 0; i < 16; ++i) {
        int prow = i * 4 + w;
        tok[(b * 257 + 1 + p0 + prow) * 256 + c0 + l] = t[l][prow];
    }
}

// ---------- pack normalized rows -> f16 hi plane, MFMA fragment order; saves norms ----------
// layout: [tile128][k32(8)][chunk16(8)][ lane(64) x 16B ]
__global__ __launch_bounds__(256) void k_pack(const float* __restrict__ src, char* __restrict__ dst,
                                              float* __restrict__ norms, int nrows) {
    __shared__ float t[16][264];
    __shared__ float pr[16][16];
    __shared__ float sn[16];
    int g = blockIdx.x;              // 16-row chunk id
    int row0 = g * 16;
    int tid = threadIdx.x;
    int rr = tid >> 4, cb = tid & 15;
    int grow = row0 + rr;
    const float* sp = src + (size_t)grow * 256 + cb * 16;
    float psum = 0.0f;
#pragma unroll
    for (int i = 0; i < 4; ++i) {
        float4 v = (grow < nrows) ? *(const float4*)(sp + i * 4) : make_float4(0.f, 0.f, 0.f, 0.f);
        *(float4*)&t[rr][cb * 16 + i * 4] = v;
        psum += v.x * v.x + v.y * v.y + v.z * v.z + v.w * v.w;
    }
    pr[rr][cb] = psum;
    __syncthreads();
    if (tid < 16) {
        float s = 0.0f;
#pragma unroll
        for (int j = 0; j < 16; ++j) s += pr[tid][j];
        float nv = fmaxf(sqrtf(s), 1e-12f);
        sn[tid] = nv;
        norms[row0 + tid] = nv;
    }
    __syncthreads();
    int c = tid & 63, pair = tid >> 6;   // pair 0..3
    int m = c & 15, jb = (c >> 4) * 8;
    float inv = 1.0f / sn[m];
    char* base = dst + (size_t)(g >> 3) * TILE_BYTES + (size_t)(g & 7) * 1024 + c * 16;
#pragma unroll
    for (int it = 0; it < 2; ++it) {
        int k32 = it * 4 + pair;         // 0..7
        const float* rowp = &t[m][k32 * 32 + jb];
        half8 o;
#pragma unroll
        for (int j = 0; j < 8; ++j) o[j] = (_Float16)(rowp[j] * inv);
        *(half8*)(base + (size_t)k32 * 8192) = o;
    }
}

// ---------- sim: f16 MFMA, LDS-staged, XCD-swizzled, MAX-ONLY epilogue ----------
__global__ __launch_bounds__(256) void k_sim(const char* __restrict__ apk, const char* __restrict__ bpk,
                                             float* __restrict__ pval) {
    __shared__ char lds[32768];      // 16 KB A-phase + 16 KB B-phase (K64)
    // XCD-aware supertile swizzle (R4-proven: FETCH 602->90 MB)
    int id = blockIdx.x;             // 0..8319
    int xcd = id & 7, r = id >> 3;
    int st = r / 104, within = r % 104;
    int stid = xcd * 10 + st;        // 0..79
    int sx = stid % 5, sy = stid / 5;
    int bx = sx * 13 + within % 13;  // 0..64
    int by = sy * 8 + within / 13;   // 0..127

    int tid = threadIdx.x;
    int ln = tid & 63, wv = tid >> 6;
    int mh = wv >> 1, nh = wv & 1;
    const char* abase = apk + (size_t)bx * TILE_BYTES;
    const char* bbase = bpk + (size_t)by * TILE_BYTES;

    f4 acc[4][4];
#pragma unroll
    for (int i = 0; i < 4; ++i)
#pragma unroll
        for (int j = 0; j < 4; ++j) acc[i][j] = (f4){0.f, 0.f, 0.f, 0.f};

    // stage phase 0 (A 16 KB + B 16 KB)
#pragma unroll
    for (int i = 0; i < 8; ++i) {
        int c = wv * 8 + i;          // 0..31
        const char* g = (c < 16 ? abase + (c << 10) : bbase + ((c - 16) << 10)) + (ln << 4);
        async16(g, lds + (c << 10));
    }

    for (int p = 0; p < 4; ++p) {
        __syncthreads();             // staged phase visible
        half8 ah[2][4], bh[2][4];
#pragma unroll
        for (int s = 0; s < 2; ++s) {
            const half8* Af = (const half8*)(lds + s * 8192);
            const half8* Bf = (const half8*)(lds + 16384 + s * 8192);
#pragma unroll
            for (int mi = 0; mi < 4; ++mi) ah[s][mi] = Af[(mh * 4 + mi) * 64 + ln];
#pragma unroll
            for (int ni = 0; ni < 4; ++ni) bh[s][ni] = Bf[(nh * 4 + ni) * 64 + ln];
        }
        __syncthreads();             // frag reads done; safe to overwrite
        if (p < 3) {
            const char* a2 = abase + (p + 1) * PHASE_BYTES;
            const char* b2 = bbase + (p + 1) * PHASE_BYTES;
#pragma unroll
            for (int i = 0; i < 8; ++i) {
                int c = wv * 8 + i;
                const char* g = (c < 16 ? a2 + (c << 10) : b2 + ((c - 16) << 10)) + (ln << 4);
                async16(g, lds + (c << 10));
            }
        }
#pragma unroll
        for (int s = 0; s < 2; ++s)
#pragma unroll
            for (int mi = 0; mi < 4; ++mi)
#pragma unroll
                for (int ni = 0; ni < 4; ++ni)
                    acc[mi][ni] = __builtin_amdgcn_mfma_f32_16x16x32_f16(ah[s][mi], bh[s][ni], acc[mi][ni], 0, 0, 0);
    }

    // max-only epilogue.  C/D: col = ln&15 (n), row = (ln>>4)*4 + reg (m)
    int col = ln & 15;
    float* srow = (float*)lds;       // [128][2]
#pragma unroll
    for (int mi = 0; mi < 4; ++mi)
#pragma unroll
        for (int rg = 0; rg < 4; ++rg) {
            float m = fmaxf(fmaxf(acc[mi][0][rg], acc[mi][1][rg]),
                            fmaxf(acc[mi][2][rg], acc[mi][3][rg]));
#pragma unroll
            for (int off = 1; off < 16; off <<= 1) m = fmaxf(m, __shfl_xor(m, off));
            if (col == 0) {
                int row = mh * 64 + mi * 16 + (ln >> 4) * 4 + rg;
                srow[row * 2 + nh] = m;
            }
        }
    __syncthreads();
    if (tid < 128) {
        float m = fmaxf(srow[tid * 2], srow[tid * 2 + 1]);
        pval[(size_t)(bx * 128 + tid) * NBY + by] = m;   // token-major
    }
}

// ---------- per token: G over block maxes, exact fp32 scan of qualifying blocks, outputs ----------
__global__ __launch_bounds__(256) void k_select(const float* __restrict__ pval,
                                                const float* __restrict__ W, const float* __restrict__ tok,
                                                const float* __restrict__ ntok, const float* __restrict__ nw,
                                                float* __restrict__ out, int* __restrict__ idxbuf,
                                                float* __restrict__ accv, unsigned int* __restrict__ used) {
    __shared__ float trow[4][260];
    int tid = threadIdx.x;
    int ln = tid & 63, w = tid >> 6;
    int t = blockIdx.x * 4 + w;               // < NTOK by grid construction
    f4 xv = *(const f4*)&tok[(size_t)t * 256 + ln * 4];
    *(f4*)&trow[w][ln * 4] = xv;
    float2 mv = *(const float2*)&pval[(size_t)t * NBY + ln * 2];   // by = 2ln, 2ln+1
    float g = fmaxf(mv.x, mv.y);
#pragma unroll
    for (int off = 1; off < 64; off <<= 1) g = fmaxf(g, __shfl_xor(g, off));
    float T = g - MWIN;
    float nt = ntok[t];
    unsigned long long m0 = __ballot(mv.x >= T);
    unsigned long long m1 = __ballot(mv.y >= T);
    float bestv = -4.0f;
    int besti = 0x7fffffff;
    for (int h = 0; h < 2; ++h) {
        unsigned long long mk = h ? m1 : m0;   // wave-uniform
        while (mk) {
            int b = __ffsll(mk) - 1;
            mk &= mk - 1;
            int by = b * 2 + h;
            int c0 = by * 128 + ln;
            const float* w0 = &W[(size_t)c0 * 256];
            const float* w1 = w0 + 64 * 256;
            float d0 = 0.f, d1 = 0.f;
#pragma unroll 8
            for (int kk = 0; kk < 64; ++kk) {
                f4 tv = *(const f4*)&trow[w][kk * 4];       // LDS broadcast
                f4 a = *(const f4*)&w0[kk * 4];
                f4 c = *(const f4*)&w1[kk * 4];
                d0 += tv.x * a.x + tv.y * a.y + tv.z * a.z + tv.w * a.w;
                d1 += tv.x * c.x + tv.y * c.y + tv.z * c.z + tv.w * c.w;
            }
            float s0 = d0 / (nt * nw[c0]);
            float s1 = d1 / (nt * nw[c0 + 64]);
            if (s0 > bestv || (s0 == bestv && c0 < besti)) { bestv = s0; besti = c0; }
            int c1 = c0 + 64;
            if (s1 > bestv || (s1 == bestv && c1 < besti)) { bestv = s1; besti = c1; }
        }
    }
    unsigned long long k = key64(bestv, besti);
#pragma unroll
    for (int off = 1; off < 64; off <<= 1) {
        unsigned long long o = __shfl_xor(k, off);
        if (o > k) k = o;
    }
    int bi = (int)(~(unsigned)(k & 0xffffffffu));
    f4 wr = *(const f4*)&W[(size_t)bi * 256 + ln * 4];
    float dx = wr.x - xv.x, dy = wr.y - xv.y, dz = wr.z - xv.z, dw = wr.w - xv.w;
    float ls = dx * dx + dy * dy + dz * dz + dw * dw;
#pragma unroll
    for (int off = 1; off < 64; off <<= 1) ls += __shfl_xor(ls, off);
    if (ln == 0) {
        atomicAdd(accv, ls);
        atomicOr(&used[bi >> 5], 1u << (bi & 31));
        idxbuf[t] = bi;
    }
    if (t % 257 == 0) *(f4*)&out[(t / 257) * 256 + ln * 4] = wr;   // fhat_class
}

// ---------- fhat_patch scatter via LDS transpose (coalesced writes) ----------
__global__ __launch_bounds__(256) void k_scatter(const int* __restrict__ idxbuf, const float* __restrict__ W,
                                                 float* __restrict__ out) {
    __shared__ float t64[64][65];
    __shared__ int sidx[64];
    int c0 = blockIdx.x * 64, p0 = blockIdx.y * 64, b = blockIdx.z;
    int tid = threadIdx.x;
    if (tid < 64) sidx[tid] = idxbuf[b * 257 + 1 + p0 + tid];
    __syncthreads();
    int l = tid & 63, w = tid >> 6;
#pragma unroll
    for (int i = 0; i < 16; ++i) {
        int p = i * 4 + w;
        t64[p][l] = W[(size_t)sidx[p] * 256 + c0 + l];
    }
    __syncthreads();
#pragma unroll
    for (int i = 0; i < 16; ++i) {
        int c = i * 4 + w;
        out[8192 + (size_t)b * 65536 + (size_t)(c0 + c) * 256 + p0 + l] = t64[l][c];
    }
}

__global__ __launch_bounds__(256) void k_final(const unsigned int* __restrict__ used,
                                               const float* __restrict__ accv, float* __restrict__ out) {
    int tid = threadIdx.x;
    int cnt = 0;
    for (int i = tid; i < VOCAB / 32; i += 256) cnt += __popc(used[i]);
#pragma unroll
    for (int off = 32; off > 0; off >>= 1) cnt += __shfl_down(cnt, off);
    __shared__ int p4[4];
    if ((tid & 63) == 0) p4[tid >> 6] = cnt;
    __syncthreads();
    if (tid == 0) {
        int c = p4[0] + p4[1] + p4[2] + p4[3];
        out[8192 + 2097152] = 1.25f * accv[0] / (float)(NTOK * 256);   // vq_loss
        out[8192 + 2097152 + 1] = 100.0f * (float)c / (float)VOCAB;    // vocab_usage
    }
}

extern "C" void kernel_launch(void* const* d_in, const int* in_sizes, int n_in,
                              void* d_out, int out_size, void* d_ws, size_t ws_size,
                              hipStream_t stream) {
    (void)in_sizes; (void)n_in; (void)out_size; (void)ws_size;
    const float* cls = (const float*)d_in[0];
    const float* patch = (const float*)d_in[1];
    const float* W = (const float*)d_in[2];
    float* out = (float*)d_out;

    char* ws = (char*)d_ws;
    float* tok = (float*)ws;                                   // 8224*256 f = 8.42 MB
    char* apk = ws + (size_t)NTOK * 256 * 4;                   // 65*65536  = 4.26 MB
    char* bpk = apk + (size_t)MTILES * TILE_BYTES;             // 128*65536 = 8.39 MB
    float* pval = (float*)(bpk + (size_t)NBY * TILE_BYTES);    // 8320*128 f = 4.26 MB
    float* ntokv = pval + (size_t)MP * NBY;                    // 8320 f
    float* nwv = ntokv + MP;                                   // 16384 f
    int* idxbuf = (int*)(nwv + VOCAB);                         // 8224 i
    float* accv = (float*)(idxbuf + NTOK);                     // 1 f
    unsigned int* used = (unsigned int*)(accv + 1);            // 512 u32

    hipMemsetAsync(accv, 0, (1 + VOCAB / 32) * sizeof(float), stream);

    k_patch<<<dim3(4, 4, NB), 256, 0, stream>>>(cls, patch, tok);
    k_pack<<<MTILES * 8, 256, 0, stream>>>(tok, apk, ntokv, NTOK);
    k_pack<<<VOCAB / 16, 256, 0, stream>>>(W, bpk, nwv, VOCAB);
    k_sim<<<MTILES * NBY, 256, 0, stream>>>(apk, bpk, pval);
    k_select<<<NTOK / 4, 256, 0, stream>>>(pval, W, tok, ntokv, nwv, out, idxbuf, accv, used);
    k_scatter<<<dim3(4, 4, NB), 256, 0, stream>>>(idxbuf, W, out);
    k_final<<<1, 256, 0, stream>>>(used, accv, out);
}